// Round 2
// baseline (413.443 us; speedup 1.0000x reference)
//
#include <hip/hip_runtime.h>
#include <hip/hip_bf16.h>
#include <hip/hip_fp16.h>

// Problem constants
#define NB 2
#define NS 2048
#define NHD 16          // heads
#define DH 64
#define NHID 1024
#define SD (NS*DH)      // 131072 elems per (b,h)
#define BHN (NB*NHD)    // 32

typedef _Float16 F16;
typedef _Float16 f16x8 __attribute__((ext_vector_type(8)));
typedef float    f32x4 __attribute__((ext_vector_type(4)));
typedef unsigned short U16;
typedef unsigned long long U64;
typedef unsigned short u16x8 __attribute__((ext_vector_type(8)));

__device__ __forceinline__ f32x4 mfma16(f16x8 a, f16x8 b, f32x4 c) {
  return __builtin_amdgcn_mfma_f32_16x16x32_f16(a, b, c, 0, 0, 0);
}

// ---------------------------------------------------------------------------
// K0: pack mask -> bitmask words (bit=1 means "masked"), convert Wo -> fp16.
// grid MUST be 1024 blocks x 256 threads.
// ---------------------------------------------------------------------------
__global__ __launch_bounds__(256) void k_prep(const int* __restrict__ mask,
                                              const float* __restrict__ Wo,
                                              U64* __restrict__ mb,
                                              F16* __restrict__ wob) {
  const int tid  = threadIdx.x;
  const int lane = tid & 63;
  const int wid  = blockIdx.x * 4 + (tid >> 6);
  const int nwords = NB * NS * (NS / 64);   // 131072
  for (int w = wid; w < nwords; w += 4096) {
    int m = mask[(size_t)w * 64 + lane];
    U64 bits = __ballot(m != 0);
    if (lane == 0) mb[w] = bits;
  }
  // Wo: 1024*1024 fp32 -> fp16. 262144 threads * 4 elems = exact cover.
  int t = blockIdx.x * 256 + tid;
  float4 f = *(const float4*)(Wo + (size_t)t * 4);
  union { U16 u[4]; F16 h[4]; } o;
  o.h[0] = (F16)f.x; o.h[1] = (F16)f.y; o.h[2] = (F16)f.z; o.h[3] = (F16)f.w;
  *(ushort4*)(wob + (size_t)t * 4) = *(ushort4*)o.u;
}

// ---------------------------------------------------------------------------
// K1: per-head QKV projection. Head panels are contiguous (raw reshape view).
// Q pre-scaled by 1/8 (folded into Wq,bq). V stored transposed [64][S].
// grid = BHN * (S/64) = 1024 blocks x 256 threads (4 waves x 16 rows).
// ---------------------------------------------------------------------------
__global__ __launch_bounds__(256) void k_proj(const float* __restrict__ qin,
    const float* __restrict__ kin, const float* __restrict__ vin,
    const float* __restrict__ Wq, const float* __restrict__ bq,
    const float* __restrict__ Wk, const float* __restrict__ bk,
    const float* __restrict__ Wv, const float* __restrict__ bv,
    F16* __restrict__ qh, F16* __restrict__ kh, F16* __restrict__ vt) {
  __shared__ float Xs[64][68];   // +4 pad: frag reads are 2-way (free)
  __shared__ F16   Ws[64][72];   // +8 pad: 16B frag reads 2-way (free)
  __shared__ float bs[64];
  __shared__ F16   Ts[64][72];   // V-tile transpose staging

  const int tid = threadIdx.x;
  const int bh = blockIdx.x >> 5;
  const int rt = blockIdx.x & 31;
  const int b = bh >> 4, h = bh & 15;
  const int r0 = rt * 64;
  const size_t xbase = (size_t)b * NS * NHID + (size_t)h * SD + (size_t)r0 * DH;
  const int w = tid >> 6, lane = tid & 63, lm = lane & 15, lg = lane >> 4;
  (void)h;

  for (int t = 0; t < 3; ++t) {
    const float* Xin = (t == 0) ? qin : (t == 1) ? kin : vin;
    const float* Wt  = (t == 0) ? Wq  : (t == 1) ? Wk  : Wv;
    const float* bt  = (t == 0) ? bq  : (t == 1) ? bk  : bv;
    const float scale = (t == 0) ? 0.125f : 1.0f;
    __syncthreads();
#pragma unroll
    for (int it = 0; it < 4; ++it) {
      int f = it * 1024 + tid * 4;
      int r = f >> 6, c = f & 63;
      float4 xv = *(const float4*)(Xin + xbase + f);
      *(float4*)&Xs[r][c] = xv;
      float4 wv4 = *(const float4*)(Wt + f);
      union { U16 u[4]; F16 h4[4]; } wo;
      wo.h4[0] = (F16)(wv4.x * scale); wo.h4[1] = (F16)(wv4.y * scale);
      wo.h4[2] = (F16)(wv4.z * scale); wo.h4[3] = (F16)(wv4.w * scale);
      *(ushort4*)&Ws[r][c] = *(ushort4*)wo.u;
    }
    if (tid < 64) bs[tid] = bt[tid] * scale;
    __syncthreads();

    // A fragments (X rows, fp32->fp16 on read)
    f16x8 af[2];
#pragma unroll
    for (int kk = 0; kk < 2; ++kk) {
      const float* sp = &Xs[w * 16 + lm][kk * 32 + lg * 8];
      union { F16 h8[8]; f16x8 v; } pk;
#pragma unroll
      for (int j = 0; j < 8; ++j) pk.h8[j] = (F16)sp[j];
      af[kk] = pk.v;
    }
    f32x4 acc[4];
#pragma unroll
    for (int nt = 0; nt < 4; ++nt) acc[nt] = (f32x4){0.f, 0.f, 0.f, 0.f};
#pragma unroll
    for (int kk = 0; kk < 2; ++kk) {
#pragma unroll
      for (int nt = 0; nt < 4; ++nt) {
        f16x8 bw = *(const f16x8*)&Ws[nt * 16 + lm][kk * 32 + lg * 8];
        acc[nt] = mfma16(af[kk], bw, acc[nt]);
      }
    }
    // Epilogue. D-layout: col = lane&15, row = (lane>>4)*4 + reg  [m89]
    if (t < 2) {
      F16* dst = (t == 0) ? qh : kh;
#pragma unroll
      for (int nt = 0; nt < 4; ++nt)
#pragma unroll
        for (int rg = 0; rg < 4; ++rg) {
          int row = w * 16 + lg * 4 + rg;
          int col = nt * 16 + lm;
          dst[(size_t)bh * SD + (size_t)(r0 + row) * DH + col] =
              (F16)(acc[nt][rg] + bs[col]);
        }
    } else {
#pragma unroll
      for (int nt = 0; nt < 4; ++nt)
#pragma unroll
        for (int rg = 0; rg < 4; ++rg) {
          int row = w * 16 + lg * 4 + rg;
          int col = nt * 16 + lm;
          Ts[row][col] = (F16)(acc[nt][rg] + bs[col]);
        }
      __syncthreads();
      // cooperative transposed store: vt[bh][d][s]
      int d = tid >> 2, qq = tid & 3;
      size_t dst = (size_t)bh * SD + (size_t)d * NS + r0 + qq * 16;
#pragma unroll
      for (int half = 0; half < 2; ++half) {
        union { F16 h8[8]; u16x8 v; } pk;
#pragma unroll
        for (int i = 0; i < 8; ++i) pk.h8[i] = Ts[qq * 16 + half * 8 + i][d];
        *(u16x8*)(vt + dst + half * 8) = pk.v;
      }
    }
  }
}

// ---------------------------------------------------------------------------
// K2: flash attention per (b,h). 64 Q-rows/block, 4 waves x 16 rows,
// KVBLK = 64. Online softmax in fp32; P goes through per-wave LDS tile.
// grid = BHN * (S/64) = 1024 blocks x 256 threads.
// ---------------------------------------------------------------------------
__global__ __launch_bounds__(256) void k_attn(const F16* __restrict__ qh,
    const F16* __restrict__ kh, const F16* __restrict__ vt,
    const U64* __restrict__ mb, F16* __restrict__ wvb) {
  __shared__ F16 Plds[4][16][72];  // per-wave P tile, padded
  const int tid = threadIdx.x;
  const int bh = blockIdx.x >> 5;
  const int qt = blockIdx.x & 31;
  const int b = bh >> 4;
  const int w = tid >> 6, lane = tid & 63, lm = lane & 15, lg = lane >> 4;
  const int q0 = qt * 64 + w * 16;
  const size_t hb = (size_t)bh * SD;

  // Q fragments held in registers for the whole KV loop (pre-scaled by 1/8)
  f16x8 aq[2];
#pragma unroll
  for (int kk = 0; kk < 2; ++kk)
    aq[kk] = *(const f16x8*)(qh + hb + (size_t)(q0 + lm) * DH + kk * 32 + lg * 8);

  f32x4 accO[4];
#pragma unroll
  for (int dn = 0; dn < 4; ++dn) accO[dn] = (f32x4){0.f, 0.f, 0.f, 0.f};
  float m[4], l[4];
#pragma unroll
  for (int rg = 0; rg < 4; ++rg) { m[rg] = -1e30f; l[rg] = 0.f; }

  const U64* mrow = mb + ((size_t)b * NS + q0 + lg * 4) * 32;

  for (int kvt = 0; kvt < 32; ++kvt) {
    const int kv0 = kvt * 64;
    // S-tile = Q @ K^T (scaled); D-layout: kcol = lm (per nt), qrow = lg*4+rg
    f32x4 accS[4];
#pragma unroll
    for (int nt = 0; nt < 4; ++nt) accS[nt] = (f32x4){0.f, 0.f, 0.f, 0.f};
#pragma unroll
    for (int kk = 0; kk < 2; ++kk) {
#pragma unroll
      for (int nt = 0; nt < 4; ++nt) {
        f16x8 bk = *(const f16x8*)(kh + hb +
            (size_t)(kv0 + nt * 16 + lm) * DH + kk * 32 + lg * 8);
        accS[nt] = mfma16(aq[kk], bk, accS[nt]);
      }
    }
    // mask: one uint64 word per (row, kv-tile); bit=1 -> -10000.0
    U64 wm[4];
#pragma unroll
    for (int rg = 0; rg < 4; ++rg) wm[rg] = mrow[(size_t)rg * 32 + kvt];
    float rmax[4];
#pragma unroll
    for (int rg = 0; rg < 4; ++rg) {
      float mx = -1e30f;
#pragma unroll
      for (int nt = 0; nt < 4; ++nt) {
        int kc = nt * 16 + lm;
        float s = ((wm[rg] >> kc) & 1ull) ? -10000.0f : accS[nt][rg];
        accS[nt][rg] = s;
        mx = fmaxf(mx, s);
      }
      rmax[rg] = mx;
    }
    // row-max across the 16 lanes sharing lg (xor over bits 0..3)
#pragma unroll
    for (int off = 1; off <= 8; off <<= 1)
#pragma unroll
      for (int rg = 0; rg < 4; ++rg)
        rmax[rg] = fmaxf(rmax[rg], __shfl_xor(rmax[rg], off, 64));
    float alpha[4], rsum[4];
#pragma unroll
    for (int rg = 0; rg < 4; ++rg) {
      float nm = fmaxf(m[rg], rmax[rg]);
      alpha[rg] = __expf(m[rg] - nm);
      m[rg] = nm;
      rsum[rg] = 0.f;
    }
#pragma unroll
    for (int nt = 0; nt < 4; ++nt)
#pragma unroll
      for (int rg = 0; rg < 4; ++rg) {
        float p = __expf(accS[nt][rg] - m[rg]);
        accS[nt][rg] = p;
        rsum[rg] += p;
      }
#pragma unroll
    for (int off = 1; off <= 8; off <<= 1)
#pragma unroll
      for (int rg = 0; rg < 4; ++rg)
        rsum[rg] += __shfl_xor(rsum[rg], off, 64);
#pragma unroll
    for (int rg = 0; rg < 4; ++rg) l[rg] = l[rg] * alpha[rg] + rsum[rg];
#pragma unroll
    for (int dn = 0; dn < 4; ++dn)
#pragma unroll
      for (int rg = 0; rg < 4; ++rg) accO[dn][rg] *= alpha[rg];
    // P (D-layout) -> LDS fp16, then re-read as MFMA A-fragments
#pragma unroll
    for (int nt = 0; nt < 4; ++nt)
#pragma unroll
      for (int rg = 0; rg < 4; ++rg)
        Plds[w][lg * 4 + rg][nt * 16 + lm] = (F16)accS[nt][rg];
    asm volatile("s_waitcnt lgkmcnt(0)" ::: "memory");
    __builtin_amdgcn_sched_barrier(0);   // rule #18: don't hoist past the wait
    // PV: O += P @ V  (V^T layout gives contiguous 16B B-fragments)
#pragma unroll
    for (int kk = 0; kk < 2; ++kk) {
      f16x8 ap = *(const f16x8*)&Plds[w][lm][kk * 32 + lg * 8];
#pragma unroll
      for (int dn = 0; dn < 4; ++dn) {
        f16x8 bv = *(const f16x8*)(vt + hb +
            (size_t)(dn * 16 + lm) * NS + kv0 + kk * 32 + lg * 8);
        accO[dn] = mfma16(ap, bv, accO[dn]);
      }
    }
  }
  float inv[4];
#pragma unroll
  for (int rg = 0; rg < 4; ++rg) inv[rg] = 1.0f / l[rg];
#pragma unroll
  for (int dn = 0; dn < 4; ++dn)
#pragma unroll
    for (int rg = 0; rg < 4; ++rg) {
      int row = q0 + lg * 4 + rg;
      int col = dn * 16 + lm;
      wvb[hb + (size_t)row * DH + col] = (F16)(accO[dn][rg] * inv[rg]);
    }
}

// ---------------------------------------------------------------------------
// K3: out[4096,1024] = wv[4096,1024] @ Wo^T + bo. 128x128 tile, BK=64,
// 4 waves in 2x2 (64x64 each), reg-staged LDS with +8 padding.
// grid = dim3(8, 32) x 256 threads.
// ---------------------------------------------------------------------------
__global__ __launch_bounds__(256) void k_oproj(const F16* __restrict__ A,
    const F16* __restrict__ Bw, const float* __restrict__ bo,
    float* __restrict__ out) {
  __shared__ F16 Ab[128][72];
  __shared__ F16 Bb[128][72];
  const int tid = threadIdx.x;
  const int tr0 = blockIdx.y * 128;
  const int tc0 = blockIdx.x * 128;
  const int w = tid >> 6, lane = tid & 63, lm = lane & 15, lg = lane >> 4;
  const int wr = (w >> 1) * 64, wc = (w & 1) * 64;
  f32x4 acc[4][4];
#pragma unroll
  for (int i = 0; i < 4; ++i)
#pragma unroll
    for (int j = 0; j < 4; ++j) acc[i][j] = (f32x4){0.f, 0.f, 0.f, 0.f};

  for (int kt = 0; kt < 16; ++kt) {
    const int k0 = kt * 64;
    __syncthreads();
#pragma unroll
    for (int it = 0; it < 4; ++it) {
      int c = it * 256 + tid;
      int r = c >> 3, c8 = c & 7;
      *(u16x8*)&Ab[r][c8 * 8] =
          *(const u16x8*)(A + (size_t)(tr0 + r) * NHID + k0 + c8 * 8);
      *(u16x8*)&Bb[r][c8 * 8] =
          *(const u16x8*)(Bw + (size_t)(tc0 + r) * NHID + k0 + c8 * 8);
    }
    __syncthreads();
#pragma unroll
    for (int kk = 0; kk < 2; ++kk) {
      f16x8 af[4], bfr[4];
#pragma unroll
      for (int mt = 0; mt < 4; ++mt)
        af[mt] = *(const f16x8*)&Ab[wr + mt * 16 + lm][kk * 32 + lg * 8];
#pragma unroll
      for (int nt = 0; nt < 4; ++nt)
        bfr[nt] = *(const f16x8*)&Bb[wc + nt * 16 + lm][kk * 32 + lg * 8];
#pragma unroll
      for (int mt = 0; mt < 4; ++mt)
#pragma unroll
        for (int nt = 0; nt < 4; ++nt)
          acc[mt][nt] = mfma16(af[mt], bfr[nt], acc[mt][nt]);
    }
  }
#pragma unroll
  for (int nt = 0; nt < 4; ++nt) {
    float bias = bo[tc0 + wc + nt * 16 + lm];
#pragma unroll
    for (int mt = 0; mt < 4; ++mt)
#pragma unroll
      for (int rg = 0; rg < 4; ++rg) {
        int row = tr0 + wr + mt * 16 + lg * 4 + rg;
        int col = tc0 + wc + nt * 16 + lm;
        out[(size_t)row * NHID + col] = acc[mt][nt][rg] + bias;
      }
  }
}

// ---------------------------------------------------------------------------
// Workspace layout (requires ws_size >= 35 MiB):
//   [0,8M)    qh  f16 [B][H][S][64]  (pre-scaled by 1/sqrt(64))
//   [8M,16M)  kh  f16 [B][H][S][64]
//   [16M,24M) vt  f16 [B][H][64][S]  (transposed)
//   [24M,32M) wvb f16 [B][H][S][64]  (== [B*S,1024] flat view for k_oproj)
//   [32M,33M) mb  u64 [B][S][S/64]   mask bitwords
//   [33M,35M) wob f16 [1024][1024]
// ---------------------------------------------------------------------------
extern "C" void kernel_launch(void* const* d_in, const int* in_sizes, int n_in,
                              void* d_out, int out_size, void* d_ws, size_t ws_size,
                              hipStream_t stream) {
  const float* q  = (const float*)d_in[0];
  const float* k  = (const float*)d_in[1];
  const float* v  = (const float*)d_in[2];
  const int*  mask = (const int*)d_in[3];
  const float* Wq = (const float*)d_in[4];
  const float* bq = (const float*)d_in[5];
  const float* Wk = (const float*)d_in[6];
  const float* bk = (const float*)d_in[7];
  const float* Wv = (const float*)d_in[8];
  const float* bv = (const float*)d_in[9];
  const float* Wo = (const float*)d_in[10];
  const float* bo = (const float*)d_in[11];
  float* out = (float*)d_out;
  char* ws = (char*)d_ws;

  F16* qh  = (F16*)(ws);
  F16* kh  = (F16*)(ws + ((size_t)8  << 20));
  F16* vt  = (F16*)(ws + ((size_t)16 << 20));
  F16* wvb = (F16*)(ws + ((size_t)24 << 20));
  U64* mb  = (U64*)(ws + ((size_t)32 << 20));
  F16* wob = (F16*)(ws + ((size_t)33 << 20));

  hipLaunchKernelGGL(k_prep, dim3(1024), dim3(256), 0, stream, mask, Wo, mb, wob);
  hipLaunchKernelGGL(k_proj, dim3(1024), dim3(256), 0, stream,
                     q, k, v, Wq, bq, Wk, bk, Wv, bv, qh, kh, vt);
  hipLaunchKernelGGL(k_attn, dim3(1024), dim3(256), 0, stream, qh, kh, vt, mb, wvb);
  hipLaunchKernelGGL(k_oproj, dim3(8, 32), dim3(256), 0, stream, wvb, wob, bo, out);
}

// Round 7
// 293.532 us; speedup vs baseline: 1.4085x; 1.4085x over previous
//
#include <hip/hip_runtime.h>
#include <hip/hip_bf16.h>
#include <hip/hip_fp16.h>

// Problem constants
#define NB 2
#define NS 2048
#define NHD 16          // heads
#define DH 64
#define NHID 1024
#define SD (NS*DH)      // 131072 elems per (b,h)
#define BHN (NB*NHD)    // 32

typedef _Float16 F16;
typedef _Float16 f16x8 __attribute__((ext_vector_type(8)));
typedef _Float16 f16x2 __attribute__((ext_vector_type(2)));
typedef float    f32x4  __attribute__((ext_vector_type(4)));
typedef float    f32x16 __attribute__((ext_vector_type(16)));
typedef unsigned short U16;
typedef unsigned long long U64;
typedef unsigned short u16x8 __attribute__((ext_vector_type(8)));

__device__ __forceinline__ f32x4 mfma16(f16x8 a, f16x8 b, f32x4 c) {
  return __builtin_amdgcn_mfma_f32_16x16x32_f16(a, b, c, 0, 0, 0);
}
__device__ __forceinline__ f32x16 mfma32(f16x8 a, f16x8 b, f32x16 c) {
  return __builtin_amdgcn_mfma_f32_32x32x16_f16(a, b, c, 0, 0, 0);
}
// v_cvt_pkrtz_f16_f32 -> packed (lo=a, hi=b) as raw u32.
__device__ __forceinline__ unsigned pk2(float a, float b) {
  return __builtin_bit_cast(unsigned, __builtin_amdgcn_cvt_pkrtz(a, b));
}

// ---------------------------------------------------------------------------
// K0: pack mask -> bitmask words (bit=1 means "masked"), convert Wo -> fp16.
// grid MUST be 1024 blocks x 256 threads.
// ---------------------------------------------------------------------------
__global__ __launch_bounds__(256) void k_prep(const int* __restrict__ mask,
                                              const float* __restrict__ Wo,
                                              U64* __restrict__ mb,
                                              F16* __restrict__ wob) {
  const int tid  = threadIdx.x;
  const int lane = tid & 63;
  const int wid  = blockIdx.x * 4 + (tid >> 6);
  const int nwords = NB * NS * (NS / 64);   // 131072
  for (int w = wid; w < nwords; w += 4096) {
    int m = mask[(size_t)w * 64 + lane];
    U64 bits = __ballot(m != 0);
    if (lane == 0) mb[w] = bits;
  }
  // Wo: 1024*1024 fp32 -> fp16. 262144 threads * 4 elems = exact cover.
  int t = blockIdx.x * 256 + tid;
  float4 f = *(const float4*)(Wo + (size_t)t * 4);
  union { U16 u[4]; F16 h[4]; } o;
  o.h[0] = (F16)f.x; o.h[1] = (F16)f.y; o.h[2] = (F16)f.z; o.h[3] = (F16)f.w;
  *(ushort4*)(wob + (size_t)t * 4) = *(ushort4*)o.u;
}

// ---------------------------------------------------------------------------
// K1: per-head QKV projection. Head panels are contiguous (raw reshape view).
// Q pre-scaled by log2(e)/8 (folds softmax's exp->exp2 conversion into Wq,bq).
// V stored transposed [64][S] with each 16-column group PERMUTED by the
// involution pi (rows 4-7 <-> 8-11 per 16-group): B-slot (hi,j) of the PV
// MFMA then holds V-row pi(hi*8+j), matching the NATIVE (un-swapped) P word
// order of the swapped-QK^T D-layout -> no cross-lane op needed in k_attn.
// grid = 1024 blocks x 256 threads.
// ---------------------------------------------------------------------------
__global__ __launch_bounds__(256) void k_proj(const float* __restrict__ qin,
    const float* __restrict__ kin, const float* __restrict__ vin,
    const float* __restrict__ Wq, const float* __restrict__ bq,
    const float* __restrict__ Wk, const float* __restrict__ bk,
    const float* __restrict__ Wv, const float* __restrict__ bv,
    F16* __restrict__ qh, F16* __restrict__ kh, F16* __restrict__ vt) {
  __shared__ float Xs[64][68];
  __shared__ F16   Ws[64][72];
  __shared__ float bs[64];
  __shared__ F16   Ts[64][72];

  const int tid = threadIdx.x;
  const int bh = blockIdx.x >> 5;
  const int rt = blockIdx.x & 31;
  const int b = bh >> 4, h = bh & 15;
  const int r0 = rt * 64;
  const size_t xbase = (size_t)b * NS * NHID + (size_t)h * SD + (size_t)r0 * DH;
  const int w = tid >> 6, lane = tid & 63, lm = lane & 15, lg = lane >> 4;
  (void)h;

  for (int t = 0; t < 3; ++t) {
    const float* Xin = (t == 0) ? qin : (t == 1) ? kin : vin;
    const float* Wt  = (t == 0) ? Wq  : (t == 1) ? Wk  : Wv;
    const float* bt  = (t == 0) ? bq  : (t == 1) ? bk  : bv;
    const float scale = (t == 0) ? 0.18033688f : 1.0f;  // log2(e)/8
    __syncthreads();
#pragma unroll
    for (int it = 0; it < 4; ++it) {
      int f = it * 1024 + tid * 4;
      int r = f >> 6, c = f & 63;
      float4 xv = *(const float4*)(Xin + xbase + f);
      *(float4*)&Xs[r][c] = xv;
      float4 wv4 = *(const float4*)(Wt + f);
      union { U16 u[4]; F16 h4[4]; } wo;
      wo.h4[0] = (F16)(wv4.x * scale); wo.h4[1] = (F16)(wv4.y * scale);
      wo.h4[2] = (F16)(wv4.z * scale); wo.h4[3] = (F16)(wv4.w * scale);
      *(ushort4*)&Ws[r][c] = *(ushort4*)wo.u;
    }
    if (tid < 64) bs[tid] = bt[tid] * scale;
    __syncthreads();

    f16x8 af[2];
#pragma unroll
    for (int kk = 0; kk < 2; ++kk) {
      const float* sp = &Xs[w * 16 + lm][kk * 32 + lg * 8];
      union { F16 h8[8]; f16x8 v; } pk;
#pragma unroll
      for (int j = 0; j < 8; ++j) pk.h8[j] = (F16)sp[j];
      af[kk] = pk.v;
    }
    f32x4 acc[4];
#pragma unroll
    for (int nt = 0; nt < 4; ++nt) acc[nt] = (f32x4){0.f, 0.f, 0.f, 0.f};
#pragma unroll
    for (int kk = 0; kk < 2; ++kk) {
#pragma unroll
      for (int nt = 0; nt < 4; ++nt) {
        f16x8 bw = *(const f16x8*)&Ws[nt * 16 + lm][kk * 32 + lg * 8];
        acc[nt] = mfma16(af[kk], bw, acc[nt]);
      }
    }
    if (t < 2) {
      F16* dst = (t == 0) ? qh : kh;
#pragma unroll
      for (int nt = 0; nt < 4; ++nt)
#pragma unroll
        for (int rg = 0; rg < 4; ++rg) {
          int row = w * 16 + lg * 4 + rg;
          int col = nt * 16 + lm;
          dst[(size_t)bh * SD + (size_t)(r0 + row) * DH + col] =
              (F16)(acc[nt][rg] + bs[col]);
        }
    } else {
#pragma unroll
      for (int nt = 0; nt < 4; ++nt)
#pragma unroll
        for (int rg = 0; rg < 4; ++rg) {
          int row = w * 16 + lg * 4 + rg;
          int col = nt * 16 + lm;
          Ts[row][col] = (F16)(acc[nt][rg] + bs[col]);
        }
      __syncthreads();
      // cooperative transposed store with per-16-group permutation pi:
      //   slot half=0: rows {0,1,2,3, 8, 9,10,11}
      //   slot half=1: rows {4,5,6,7,12,13,14,15}
      int d = tid >> 2, qq = tid & 3;
      size_t dst = (size_t)bh * SD + (size_t)d * NS + r0 + qq * 16;
#pragma unroll
      for (int half = 0; half < 2; ++half) {
        union { F16 h8[8]; u16x8 v; } pk;
#pragma unroll
        for (int i = 0; i < 8; ++i) {
          int r = (i < 4) ? (half * 4 + i) : (i + 4 + half * 4);
          pk.h8[i] = Ts[qq * 16 + r][d];
        }
        *(u16x8*)(vt + dst + half * 8) = pk.v;
      }
    }
  }
}

// ---------------------------------------------------------------------------
// K2: flash attention, swapped-QK^T 32x32 structure (in-register softmax).
// 4 waves/block, each wave owns a 32-row Q tile; KVBLK=64; defer-max (THR=8
// in log2 domain); mask applied as post-exp zeroing from bitwords.
// P->PV needs NO cross-lane movement: the QK^T D-layout leaves lane (lq,hi)
// holding k-local {0..3,8..11}+4hi per 16-group, packed sequentially into
// 4 words; vt's 16-groups are pre-permuted (k_proj) so the MFMA B-slot
// (hi,j) holds exactly the matching V row. l summed from the same packed
// words (disjoint across the hi pair; combined by the final shfl_xor(32)).
// grid = 512 blocks x 256 threads.
// ---------------------------------------------------------------------------
__global__ __launch_bounds__(256) void k_attn(const F16* __restrict__ qh,
    const F16* __restrict__ kh, const F16* __restrict__ vt,
    const U64* __restrict__ mb, F16* __restrict__ wvb) {
  __shared__ float bl[4][32];   // per-wave alpha / 1/l broadcast
  const int tid = threadIdx.x;
  const int w = tid >> 6, l = tid & 63;
  const int lq = l & 31, hi = l >> 5;
  const int tile = blockIdx.x * 4 + w;   // 0..2047
  const int bh = tile >> 6;
  const int qt = tile & 63;
  const int b = bh >> 4;
  const int q0 = qt * 32;
  const size_t hb = (size_t)bh * SD;

  // Q B-fragments (pre-scaled by log2e/8): qf[kt] = Q[q0+lq][kt*16+hi*8 ..+7]
  f16x8 qf[4];
#pragma unroll
  for (int kt = 0; kt < 4; ++kt)
    qf[kt] = *(const f16x8*)(qh + hb + (size_t)(q0 + lq) * DH + kt * 16 + hi * 8);

  f32x16 accO0, accO1;
#pragma unroll
  for (int r = 0; r < 16; ++r) { accO0[r] = 0.f; accO1[r] = 0.f; }
  float m_run = -1e30f, l_run = 0.f;

  const U64* mrow = mb + ((size_t)b * NS + q0 + lq) * (NS / 64);
  const F16* kb = kh + hb;
  const F16* vb = vt + hb;
  const f16x2 one2 = {(F16)1.f, (F16)1.f};

  for (int c64 = 0; c64 < 32; ++c64) {
    const int kv0 = c64 * 64;
    U64 wm = mrow[c64];                 // hoisted: hide latency under QK^T
    f32x16 s0, s1;
#pragma unroll
    for (int r = 0; r < 16; ++r) { s0[r] = 0.f; s1[r] = 0.f; }
    // S = K @ Q^T (swapped): D col = q = lane&31, row = k-local
#pragma unroll
    for (int kt = 0; kt < 4; ++kt) {
      f16x8 kf0 = *(const f16x8*)(kb + (size_t)(kv0 + lq) * DH + kt * 16 + hi * 8);
      f16x8 kf1 = *(const f16x8*)(kb + (size_t)(kv0 + 32 + lq) * DH + kt * 16 + hi * 8);
      s0 = mfma32(kf0, qf[kt], s0);
      s1 = mfma32(kf1, qf[kt], s1);
    }
    // chunk max over RAW scores (valid softmax shift; masked cols zeroed later)
    float cmax = fmaxf(s0[0], s1[0]);
#pragma unroll
    for (int r = 1; r < 16; ++r) cmax = fmaxf(cmax, fmaxf(s0[r], s1[r]));
    cmax = fmaxf(cmax, __shfl_xor(cmax, 32, 64));
    // defer-max: rescale only when max grew by >8 (log2 domain; P <= 256)
    if (__any(cmax > m_run + 8.0f)) {
      float nm = fmaxf(m_run, cmax);
      float al = __builtin_amdgcn_exp2f(m_run - nm);
      m_run = nm;
      l_run *= al;
      bl[w][lq] = al;
      asm volatile("s_waitcnt lgkmcnt(0)" ::: "memory");
      __builtin_amdgcn_sched_barrier(0);
      // accO reg r holds q-row (r&3)+8*(r>>2)+4*hi -> group g reads bl[g*8+4hi..+3]
      float4 g0 = *(const float4*)&bl[w][hi * 4];
      float4 g1 = *(const float4*)&bl[w][8 + hi * 4];
      float4 g2 = *(const float4*)&bl[w][16 + hi * 4];
      float4 g3 = *(const float4*)&bl[w][24 + hi * 4];
      float av[16] = {g0.x,g0.y,g0.z,g0.w, g1.x,g1.y,g1.z,g1.w,
                      g2.x,g2.y,g2.z,g2.w, g3.x,g3.y,g3.z,g3.w};
#pragma unroll
      for (int r = 0; r < 16; ++r) { accO0[r] *= av[r]; accO1[r] *= av[r]; }
    }
    // p = exp2(s - m)
#pragma unroll
    for (int r = 0; r < 16; ++r) {
      s0[r] = __builtin_amdgcn_exp2f(s0[r] - m_run);
      s1[r] = __builtin_amdgcn_exp2f(s1[r] - m_run);
    }
    // mask: bit=1 -> p=0. reg r of s{rt}: k = rt*32 + (r&3)+8*(r>>2)+4*hi
    unsigned u0 = ((unsigned)wm) >> (hi * 4);
    unsigned u1 = ((unsigned)(wm >> 32)) >> (hi * 4);
#pragma unroll
    for (int r = 0; r < 16; ++r) {
      const int sh = (r & 3) + 8 * (r >> 2);
      s0[r] = ((u0 >> sh) & 1u) ? 0.f : s0[r];
      s1[r] = ((u1 >> sh) & 1u) ? 0.f : s1[r];
    }
    // pack -> f16 pairs in NATIVE order = PV A-frags (V pre-permuted);
    // l via fdot2 on the same words.
#pragma unroll
    for (int c = 0; c < 4; ++c) {
      const int rb = (c & 1) * 8;
      unsigned w0, w1, w2, w3;
      if (c < 2) {
        w0 = pk2(s0[rb + 0], s0[rb + 1]);
        w1 = pk2(s0[rb + 2], s0[rb + 3]);
        w2 = pk2(s0[rb + 4], s0[rb + 5]);
        w3 = pk2(s0[rb + 6], s0[rb + 7]);
      } else {
        w0 = pk2(s1[rb + 0], s1[rb + 1]);
        w1 = pk2(s1[rb + 2], s1[rb + 3]);
        w2 = pk2(s1[rb + 4], s1[rb + 5]);
        w3 = pk2(s1[rb + 6], s1[rb + 7]);
      }
      union { unsigned u[4]; f16x8 v; } P;
      P.u[0] = w0; P.u[1] = w1; P.u[2] = w2; P.u[3] = w3;
      l_run = __builtin_amdgcn_fdot2(__builtin_bit_cast(f16x2, w0), one2, l_run, false);
      l_run = __builtin_amdgcn_fdot2(__builtin_bit_cast(f16x2, w1), one2, l_run, false);
      l_run = __builtin_amdgcn_fdot2(__builtin_bit_cast(f16x2, w2), one2, l_run, false);
      l_run = __builtin_amdgcn_fdot2(__builtin_bit_cast(f16x2, w3), one2, l_run, false);
      f16x8 v0 = *(const f16x8*)(vb + (size_t)lq * NS + kv0 + c * 16 + hi * 8);
      f16x8 v1 = *(const f16x8*)(vb + (size_t)(32 + lq) * NS + kv0 + c * 16 + hi * 8);
      accO0 = mfma32(P.v, v0, accO0);
      accO1 = mfma32(P.v, v1, accO1);
    }
  }
  // epilogue: combine l halves, broadcast 1/l to PV-output layout, store
  l_run += __shfl_xor(l_run, 32, 64);
  float inv = 1.0f / l_run;
  bl[w][lq] = inv;
  asm volatile("s_waitcnt lgkmcnt(0)" ::: "memory");
  __builtin_amdgcn_sched_barrier(0);
  float4 g0 = *(const float4*)&bl[w][hi * 4];
  float4 g1 = *(const float4*)&bl[w][8 + hi * 4];
  float4 g2 = *(const float4*)&bl[w][16 + hi * 4];
  float4 g3 = *(const float4*)&bl[w][24 + hi * 4];
  float iv[16] = {g0.x,g0.y,g0.z,g0.w, g1.x,g1.y,g1.z,g1.w,
                  g2.x,g2.y,g2.z,g2.w, g3.x,g3.y,g3.z,g3.w};
#pragma unroll
  for (int r = 0; r < 16; ++r) {
    const int row = q0 + (r & 3) + 8 * (r >> 2) + 4 * hi;
    wvb[hb + (size_t)row * DH + lq]      = (F16)(accO0[r] * iv[r]);
    wvb[hb + (size_t)row * DH + 32 + lq] = (F16)(accO1[r] * iv[r]);
  }
}

// ---------------------------------------------------------------------------
// K3: out[4096,1024] = wv @ Wo^T + bo. 64x64 tile for 4 blocks/CU:
// grid = dim3(16, 64) x 256 threads, BK=64.
// ---------------------------------------------------------------------------
__global__ __launch_bounds__(256) void k_oproj(const F16* __restrict__ A,
    const F16* __restrict__ Bw, const float* __restrict__ bo,
    float* __restrict__ out) {
  __shared__ F16 As[64][72];
  __shared__ F16 Bs[64][72];
  const int tid = threadIdx.x;
  const int tc0 = blockIdx.x * 64;
  const int tr0 = blockIdx.y * 64;
  const int w = tid >> 6, lane = tid & 63, lm = lane & 15, lg = lane >> 4;
  f32x4 acc[4];
#pragma unroll
  for (int j = 0; j < 4; ++j) acc[j] = (f32x4){0.f, 0.f, 0.f, 0.f};

  for (int kt = 0; kt < 16; ++kt) {
    const int k0 = kt * 64;
    __syncthreads();
#pragma unroll
    for (int it = 0; it < 2; ++it) {
      int c = it * 256 + tid;
      int r = c >> 3, c8 = c & 7;
      *(u16x8*)&As[r][c8 * 8] =
          *(const u16x8*)(A + (size_t)(tr0 + r) * NHID + k0 + c8 * 8);
      *(u16x8*)&Bs[r][c8 * 8] =
          *(const u16x8*)(Bw + (size_t)(tc0 + r) * NHID + k0 + c8 * 8);
    }
    __syncthreads();
#pragma unroll
    for (int kk = 0; kk < 2; ++kk) {
      f16x8 af = *(const f16x8*)&As[w * 16 + lm][kk * 32 + lg * 8];
#pragma unroll
      for (int nt = 0; nt < 4; ++nt) {
        f16x8 bfr = *(const f16x8*)&Bs[nt * 16 + lm][kk * 32 + lg * 8];
        acc[nt] = mfma16(af, bfr, acc[nt]);
      }
    }
  }
#pragma unroll
  for (int nt = 0; nt < 4; ++nt) {
    float bias = bo[tc0 + nt * 16 + lm];
#pragma unroll
    for (int rg = 0; rg < 4; ++rg) {
      int row = tr0 + w * 16 + lg * 4 + rg;
      int col = tc0 + nt * 16 + lm;
      out[(size_t)row * NHID + col] = acc[nt][rg] + bias;
    }
  }
}

// ---------------------------------------------------------------------------
// Workspace layout (<= 35 MiB, proven safe):
//   [0,8M)    qh  f16 [B][H][S][64]  (pre-scaled by log2e/8)
//   [8M,16M)  kh  f16 [B][H][S][64]
//   [16M,24M) vt  f16 [B][H][64][S]  (transposed, 16-groups pi-permuted)
//   [24M,32M) wvb f16 [B][H][S][64]  (== [B*S,1024] flat view for k_oproj)
//   [32M,33M) mb  u64 [B][S][S/64]   mask bitwords
//   [33M,35M) wob f16 [1024][1024]
// ---------------------------------------------------------------------------
extern "C" void kernel_launch(void* const* d_in, const int* in_sizes, int n_in,
                              void* d_out, int out_size, void* d_ws, size_t ws_size,
                              hipStream_t stream) {
  const float* q  = (const float*)d_in[0];
  const float* k  = (const float*)d_in[1];
  const float* v  = (const float*)d_in[2];
  const int*  mask = (const int*)d_in[3];
  const float* Wq = (const float*)d_in[4];
  const float* bq = (const float*)d_in[5];
  const float* Wk = (const float*)d_in[6];
  const float* bk = (const float*)d_in[7];
  const float* Wv = (const float*)d_in[8];
  const float* bv = (const float*)d_in[9];
  const float* Wo = (const float*)d_in[10];
  const float* bo = (const float*)d_in[11];
  float* out = (float*)d_out;
  char* ws = (char*)d_ws;

  F16* qh  = (F16*)(ws);
  F16* kh  = (F16*)(ws + ((size_t)8  << 20));
  F16* vt  = (F16*)(ws + ((size_t)16 << 20));
  F16* wvb = (F16*)(ws + ((size_t)24 << 20));
  U64* mb  = (U64*)(ws + ((size_t)32 << 20));
  F16* wob = (F16*)(ws + ((size_t)33 << 20));

  hipLaunchKernelGGL(k_prep, dim3(1024), dim3(256), 0, stream, mask, Wo, mb, wob);
  hipLaunchKernelGGL(k_proj, dim3(1024), dim3(256), 0, stream,
                     q, k, v, Wq, bq, Wk, bk, Wv, bv, qh, kh, vt);
  hipLaunchKernelGGL(k_attn, dim3(512), dim3(256), 0, stream, qh, kh, vt, mb, wvb);
  hipLaunchKernelGGL(k_oproj, dim3(16, 64), dim3(256), 0, stream, wvb, wob, bo, out);
}